// Round 4
// baseline (340.032 us; speedup 1.0000x reference)
//
#include <hip/hip_runtime.h>

#define HW 262144            // 512*512 pixels per image
#define NCHUNK 32            // chunks per image
#define CHUNK 8192           // pixels per chunk
#define SBINS 512            // sample histogram bins (8 exp | 1 mantissa)
#define POS_THRESH 0.1f
#define FALLBACK_POS 1000.0f

// ---------------------------------------------------------------------------
// Kernel A: sampled count-only histogram (1/8 of pixels: chunks 2,10,18,26
// of each image). 4 KB LDS, u32 atomics. Only purpose: locate a coarse
// top-k pivot t per image-op. ~40 MB traffic.
// ---------------------------------------------------------------------------
__global__ __launch_bounds__(256) void sample_hist(
    const float* __restrict__ rlab, const float* __restrict__ alab,
    const float* __restrict__ rpre, const float* __restrict__ apre,
    const float* __restrict__ mask,
    unsigned int* __restrict__ g_hist)      // [2*B][SBINS]
{
    __shared__ unsigned int s_h[2][SBINS];
    const int tid = threadIdx.x;
    const int img = blockIdx.y;
    const int c   = blockIdx.x * 8 + 2;     // sampled chunk ids

    for (int i = tid; i < 2 * SBINS; i += 256) ((unsigned int*)s_h)[i] = 0u;
    __syncthreads();

    const size_t base = (size_t)img * HW + (size_t)c * CHUNK;
    const float4* rl4 = (const float4*)(rlab + base);
    const float4* al4 = (const float4*)(alab + base);
    const float4* rp4 = (const float4*)(rpre + base);
    const float4* ap4 = (const float4*)(apre + base);
    const float4* m4  = (const float4*)(mask + base);

    auto proc = [&](float lab, float pre, float mm, int op) {
        float d = pre - lab;
        float l = d * d * mm;
        if (!(lab > POS_THRESH)) {
            unsigned int b = __float_as_uint(l) >> 22;   // monotone for l>=0
            if (b > 510u) b = 510u;                      // keep finite on decode
            atomicAdd(&s_h[op][b], 1u);
        }
    };

    const int NV = CHUNK / 4;               // 2048 float4
    for (int i0 = tid; i0 < NV; i0 += 512) {
        const int i1 = i0 + 256;
        float4 rl0 = rl4[i0], rl1 = rl4[i1];
        float4 al0 = al4[i0], al1 = al4[i1];
        float4 rp0 = rp4[i0], rp1 = rp4[i1];
        float4 ap0 = ap4[i0], ap1 = ap4[i1];
        float4 m0  = m4[i0],  m1  = m4[i1];
        proc(rl0.x, rp0.x, m0.x, 0); proc(al0.x, ap0.x, m0.x, 1);
        proc(rl0.y, rp0.y, m0.y, 0); proc(al0.y, ap0.y, m0.y, 1);
        proc(rl0.z, rp0.z, m0.z, 0); proc(al0.z, ap0.z, m0.z, 1);
        proc(rl0.w, rp0.w, m0.w, 0); proc(al0.w, ap0.w, m0.w, 1);
        proc(rl1.x, rp1.x, m1.x, 0); proc(al1.x, ap1.x, m1.x, 1);
        proc(rl1.y, rp1.y, m1.y, 0); proc(al1.y, ap1.y, m1.y, 1);
        proc(rl1.z, rp1.z, m1.z, 0); proc(al1.z, ap1.z, m1.z, 1);
        proc(rl1.w, rp1.w, m1.w, 0); proc(al1.w, ap1.w, m1.w, 1);
    }
    __syncthreads();

    const int j0 = img * 2;
    for (int i = tid; i < 2 * SBINS; i += 256) {
        const int op = i >> 9, b = i & (SBINS - 1);
        unsigned int v = s_h[op][b];
        if (v) atomicAdd(&g_hist[(size_t)(j0 + op) * SBINS + b], v);
    }
}

// ---------------------------------------------------------------------------
// Kernel B: per image-op, scan sampled histogram top-down for the pivot t
// (lower edge of the bin where sampled cum count crosses neg_rto*p_sample).
// Pivot accuracy only matters to 2nd order (CVaR identity in finalize).
// ---------------------------------------------------------------------------
__global__ __launch_bounds__(64) void find_t(
    const unsigned int* __restrict__ g_hist,
    const int* __restrict__ nrto_p, float* __restrict__ g_t)
{
    __shared__ unsigned int s_b[SBINS];
    const int j = blockIdx.x, tid = threadIdx.x;
    for (int i = tid; i < SBINS; i += 64) s_b[i] = g_hist[(size_t)j * SBINS + i];
    __syncthreads();

    if (tid == 0) {
        const float nr = (float)(*nrto_p);
        long long ns = 0;
        for (int i = 0; i < SBINS; ++i) ns += s_b[i];
        const long long samp = 4LL * CHUNK;            // 32768 sampled pixels
        const long long ps   = samp - ns;              // sampled positives
        // sampled-units target: k_s = k_f * (1/8) = nr * p_sample
        const float k_s = nr * ((ps > 0) ? (float)ps : FALLBACK_POS / 8.0f);
        float t = 0.f;
        long long cum = 0;
        for (int b = SBINS - 1; b >= 0; --b) {
            cum += s_b[b];
            if ((float)cum >= k_s) { t = __uint_as_float((unsigned)b << 22); break; }
        }
        g_t[j] = t;
    }
}

// ---------------------------------------------------------------------------
// Kernel C: the main streaming pass. NO LDS histogram, NO divergent atomics —
// 10 predicated register accumulators per thread:
//   per map: {pos_count, pos_sum, neg_sum, count_above_t, sum_above_t}
// One block-reduce + 10 global float atomics per block.
// ---------------------------------------------------------------------------
__global__ __launch_bounds__(256) void stream_main(
    const float* __restrict__ rlab, const float* __restrict__ alab,
    const float* __restrict__ rpre, const float* __restrict__ apre,
    const float* __restrict__ mask, const float* __restrict__ g_t,
    float* __restrict__ g_acc)              // [2*B][5]
{
    __shared__ float s_red[4][10];
    const int tid = threadIdx.x;
    const int img = blockIdx.y, sl = blockIdx.x;
    const int j0  = img * 2;
    const float tr = g_t[j0], ta = g_t[j0 + 1];

    const size_t base = (size_t)img * HW + (size_t)sl * CHUNK;
    const float4* rl4 = (const float4*)(rlab + base);
    const float4* al4 = (const float4*)(alab + base);
    const float4* rp4 = (const float4*)(rpre + base);
    const float4* ap4 = (const float4*)(apre + base);
    const float4* m4  = (const float4*)(mask + base);

    float a0 = 0, a1 = 0, a2 = 0, a3 = 0, a4 = 0;   // region
    float b0 = 0, b1 = 0, b2 = 0, b3 = 0, b4 = 0;   // affinity

    auto proc = [&](float lab, float pre, float mm, float t,
                    float& pc, float& sp, float& sn, float& na, float& sa) {
        float d = pre - lab;
        float l = d * d * mm;
        bool pos = lab > POS_THRESH;
        float ln = pos ? 0.f : l;               // neg_region value
        sp += pos ? l : 0.f;
        pc += pos ? 1.f : 0.f;
        sn += ln;
        bool ab = ln > t;                       // strict >, pivots are bin edges
        sa += ab ? ln : 0.f;
        na += ab ? 1.f : 0.f;
    };

    const int NV = CHUNK / 4;                   // 2048 float4
    for (int i0 = tid; i0 < NV; i0 += 512) {
        const int i1 = i0 + 256;
        float4 rl0 = rl4[i0], rl1 = rl4[i1];
        float4 al0 = al4[i0], al1 = al4[i1];
        float4 rp0 = rp4[i0], rp1 = rp4[i1];
        float4 ap0 = ap4[i0], ap1 = ap4[i1];
        float4 m0  = m4[i0],  m1  = m4[i1];

        proc(rl0.x, rp0.x, m0.x, tr, a0, a1, a2, a3, a4);
        proc(al0.x, ap0.x, m0.x, ta, b0, b1, b2, b3, b4);
        proc(rl0.y, rp0.y, m0.y, tr, a0, a1, a2, a3, a4);
        proc(al0.y, ap0.y, m0.y, ta, b0, b1, b2, b3, b4);
        proc(rl0.z, rp0.z, m0.z, tr, a0, a1, a2, a3, a4);
        proc(al0.z, ap0.z, m0.z, ta, b0, b1, b2, b3, b4);
        proc(rl0.w, rp0.w, m0.w, tr, a0, a1, a2, a3, a4);
        proc(al0.w, ap0.w, m0.w, ta, b0, b1, b2, b3, b4);

        proc(rl1.x, rp1.x, m1.x, tr, a0, a1, a2, a3, a4);
        proc(al1.x, ap1.x, m1.x, ta, b0, b1, b2, b3, b4);
        proc(rl1.y, rp1.y, m1.y, tr, a0, a1, a2, a3, a4);
        proc(al1.y, ap1.y, m1.y, ta, b0, b1, b2, b3, b4);
        proc(rl1.z, rp1.z, m1.z, tr, a0, a1, a2, a3, a4);
        proc(al1.z, ap1.z, m1.z, ta, b0, b1, b2, b3, b4);
        proc(rl1.w, rp1.w, m1.w, tr, a0, a1, a2, a3, a4);
        proc(al1.w, ap1.w, m1.w, ta, b0, b1, b2, b3, b4);
    }

    // wave shuffle-reduce all 10 accumulators
    for (int off = 32; off > 0; off >>= 1) {
        a0 += __shfl_down(a0, off); a1 += __shfl_down(a1, off);
        a2 += __shfl_down(a2, off); a3 += __shfl_down(a3, off);
        a4 += __shfl_down(a4, off);
        b0 += __shfl_down(b0, off); b1 += __shfl_down(b1, off);
        b2 += __shfl_down(b2, off); b3 += __shfl_down(b3, off);
        b4 += __shfl_down(b4, off);
    }
    const int wave = tid >> 6, lane = tid & 63;
    if (lane == 0) {
        s_red[wave][0] = a0; s_red[wave][1] = a1; s_red[wave][2] = a2;
        s_red[wave][3] = a3; s_red[wave][4] = a4;
        s_red[wave][5] = b0; s_red[wave][6] = b1; s_red[wave][7] = b2;
        s_red[wave][8] = b3; s_red[wave][9] = b4;
    }
    __syncthreads();
    if (tid < 10) {
        float v = s_red[0][tid] + s_red[1][tid] + s_red[2][tid] + s_red[3][tid];
        const int op = tid / 5, f = tid % 5;
        atomicAdd(&g_acc[(size_t)(j0 + op) * 5 + f], v);
    }
}

// ---------------------------------------------------------------------------
// Kernel D: finalize. topk(k) = S_{>t} + (k - N_{>t}) * t  (CVaR identity,
// 2nd-order exact in t). Mirrors reference branches, sums over image-ops.
// ---------------------------------------------------------------------------
__global__ __launch_bounds__(128) void finalize(
    const float* __restrict__ g_acc, const float* __restrict__ g_t,
    const int* __restrict__ nrto_p, float* __restrict__ out,
    int J, int batch)
{
    __shared__ float s_sum[2];
    const int tid = threadIdx.x;
    const float nr = (float)(*nrto_p);

    float acc = 0.f;
    for (int j = tid; j < J; j += 128) {
        const float pc = g_acc[j * 5 + 0], sp = g_acc[j * 5 + 1];
        const float sn = g_acc[j * 5 + 2], na = g_acc[j * 5 + 3];
        const float sa = g_acc[j * 5 + 4];
        const float t  = g_t[j];
        const float p  = pc;
        const float n  = (float)HW - pc;

        const double pos_loss = (p > 0.f) ? (double)sp / (double)p : 0.0;
        const float  p_eff = (p > 0.f) ? p : FALLBACK_POS;
        const float  k_f   = nr * p_eff;
        const float  kk    = floorf(k_f);          // int(neg_rto * p) truncation

        double topk = 0.0;
        if (kk > 0.f) {
            if (n <= kk) topk = (double)sn;        // zeros pad beyond n
            else         topk = (double)sa + (double)(kk - na) * (double)t;
        }

        const bool use_all = (p > 0.f) && (n < k_f);
        const double neg_loss = use_all
            ? (double)sn / (double)fmaxf(n, 1.f)
            : topk / (double)k_f;
        acc += (float)(pos_loss + neg_loss);
    }

    for (int off = 32; off > 0; off >>= 1) acc += __shfl_down(acc, off);
    if ((tid & 63) == 0) s_sum[tid >> 6] = acc;
    __syncthreads();
    if (tid == 0) out[0] = (s_sum[0] + s_sum[1]) / (float)batch;
}

// ---------------------------------------------------------------------------
extern "C" void kernel_launch(void* const* d_in, const int* in_sizes, int n_in,
                              void* d_out, int out_size, void* d_ws, size_t ws_size,
                              hipStream_t stream) {
    const float* rlab = (const float*)d_in[0];
    const float* alab = (const float*)d_in[1];
    const float* rpre = (const float*)d_in[2];
    const float* apre = (const float*)d_in[3];
    const float* mask = (const float*)d_in[4];
    const int*   nrto = (const int*)d_in[5];

    const int B = in_sizes[0] / HW;            // 64
    const int J = 2 * B;                       // image-ops

    unsigned int* g_hist = (unsigned int*)d_ws;                          // J*SBINS u32
    float* g_acc = (float*)((char*)d_ws + (size_t)J * SBINS * 4);        // J*5 f32
    float* g_t   = g_acc + (size_t)J * 5;                                // J f32

    const size_t zbytes = (size_t)J * SBINS * 4 + (size_t)J * 5 * 4;
    hipMemsetAsync(d_ws, 0, zbytes, stream);

    sample_hist<<<dim3(4, B), 256, 0, stream>>>(rlab, alab, rpre, apre, mask, g_hist);
    find_t<<<J, 64, 0, stream>>>(g_hist, nrto, g_t);
    stream_main<<<dim3(NCHUNK, B), 256, 0, stream>>>(rlab, alab, rpre, apre, mask,
                                                     g_t, g_acc);
    finalize<<<1, 128, 0, stream>>>(g_acc, g_t, nrto, (float*)d_out, J, B);
}